// Round 14
// baseline (107.335 us; speedup 1.0000x reference)
//
#include <hip/hip_runtime.h>
#include <math.h>

#define B_   64
#define NPB  3468            // points (visual words) per batch
#define NPTS (B_ * NPB)      // 221952
#define KC   248
#define D_   64
#define NV   (KC * D_)       // 15872 per-batch vlad elements
#define OCT  34              // norms: chunks per batch (N4CH = 1632 = 6*256+96)
#define N4PB (NPB * D_ / 4)  // 55488 float4s per batch
#define N4CH (N4PB / OCT)    // 1632 float4s per chunk
#define CHPB 55              // aggregation chunks per batch
#define APAD 65
#define SLIM 64              // sorted code rows staged in LDS
#define NBLK (NPTS / 256)    // 867 point-blocks
#define SCB  1024            // persistent scan blocks (4/CU, 16 waves/CU)
#define ZBLK 128             // zeroing blocks in prep
#define ZN4  261888          // float4s in zero region (counts+Sacc+vacc)

typedef float nf4 __attribute__((ext_vector_type(4)));   // builtin-compatible vec4

// ------------------------- workspace offsets (bytes) -------------------------
#define OFF_PARTIAL 0u        // 64*34*64*4 = 557056
#define OFF_COUNTS  557056u   // 63488   -- zero region start
#define OFF_SACC    620544u   // 63488
#define OFF_VACC    684032u   // 4063232 -- zero region end = 4747264
#define OFF_KOUT    4747264u  // 221952
#define OFF_RINV    4969216u  // 887808
#define OFF_RANK    5857024u  // 443904
#define OFF_SPU     6300928u  // 887808  (packed sorted: pidx<<8 | k)
#define OFF_HNS     7188736u  // 1024
#define OFF_KSRT    7189760u  // 256
#define OFF_SCODES  7190016u  // 16384 (first SLIM sorted rows) -> end 7206400

// ===== pass 1: persistent-block column-sumsq scan + code sort + zeroing
__global__ __launch_bounds__(256) void prep_kernel(const float* __restrict__ feat,
                                                   const float* __restrict__ codes,
                                                   float* __restrict__ partial,
                                                   float* __restrict__ hns,
                                                   unsigned char* __restrict__ ksrt,
                                                   float* __restrict__ scodes,
                                                   float4* __restrict__ zbase) {
    int t = threadIdx.x;
    if (blockIdx.x > SCB) {                 // zeroing blocks
        int z = blockIdx.x - (SCB + 1);
        const float4 zf = make_float4(0.f, 0.f, 0.f, 0.f);
        for (int i = z * 256 + t; i < ZN4; i += ZBLK * 256) zbase[i] = zf;
        return;
    }
    if (blockIdx.x == SCB) {                // code half-norms + hn-sort block
        __shared__ float shn[KC];
        int lane = t & 63, wvid = t >> 6;
        for (int base2 = 0; base2 < KC * D_; base2 += 256) {
            float c = codes[base2 + t];
            float cc = c * c;
            #pragma unroll
            for (int off = 32; off > 0; off >>= 1) cc += __shfl_down(cc, off);
            if (lane == 0) shn[(base2 >> 6) + wvid] = 0.5f * cc;
        }
        __syncthreads();
        if (t < KC) {
            float myhn = shn[t];
            int rank = 0;
            for (int j = 0; j < KC; ++j) {
                float h = shn[j];
                rank += (h < myhn) || (h == myhn && j < t);
            }
            hns[rank] = myhn;
            ksrt[rank] = (unsigned char)t;
            if (rank < SLIM) {              // stage only rows assign keeps in LDS
                const float4* src = (const float4*)(codes + t * D_);
                float4* dst = (float4*)(scodes + rank * D_);
                #pragma unroll
                for (int j = 0; j < 16; ++j) dst[j] = src[j];
            }
        }
        return;
    }
    // persistent grid-stride over 2176 chunks: TLP (4 waves/SIMD) + 6-deep MLP
    __shared__ float4 red[256];
    const nf4* fv = (const nf4*)feat;
    for (int ch = blockIdx.x; ch < B_ * OCT; ch += SCB) {
        int b = ch / OCT, o = ch % OCT;
        size_t base4 = (size_t)b * N4PB + (size_t)o * N4CH;
        float ax = 0.f, ay = 0.f, az = 0.f, aw = 0.f;
        {
            nf4 r[6];
            #pragma unroll
            for (int j = 0; j < 6; ++j)
                r[j] = __builtin_nontemporal_load(&fv[base4 + t + j * 256]);
            #pragma unroll
            for (int j = 0; j < 6; ++j) {
                ax += r[j].x * r[j].x; ay += r[j].y * r[j].y;
                az += r[j].z * r[j].z; aw += r[j].w * r[j].w;
            }
            if (t < 96) {                   // tail 1536..1631
                nf4 a = __builtin_nontemporal_load(&fv[base4 + 1536 + t]);
                ax += a.x * a.x; ay += a.y * a.y; az += a.z * a.z; aw += a.w * a.w;
            }
        }
        // N4CH%16==0 -> thread t's float4 always covers dim-group t&15
        red[t] = make_float4(ax, ay, az, aw);
        __syncthreads();
        if (t < 16) {
            float sx = 0.f, sy = 0.f, sz = 0.f, sw = 0.f;
            #pragma unroll
            for (int j = 0; j < 16; ++j) {
                float4 a = red[t + 16 * j];
                sx += a.x; sy += a.y; sz += a.z; sw += a.w;
            }
            float* dst = partial + ((size_t)ch) * D_ + 4 * t;
            dst[0] = sx; dst[1] = sy; dst[2] = sz; dst[3] = sw;
        }
        __syncthreads();                    // red reuse guard
    }
}

// ===== pass 2: assignment (per-block inv-norm derive + CS pruning + 2-level rank)
__global__ __launch_bounds__(256) void assign_kernel(const float* __restrict__ feat,
                                                     const float* __restrict__ codes,
                                                     const float* __restrict__ scodes,
                                                     const float* __restrict__ partial,
                                                     const float* __restrict__ hns,
                                                     const unsigned char* __restrict__ ksrt,
                                                     unsigned char* __restrict__ kout,
                                                     float* __restrict__ rinvout,
                                                     unsigned short* __restrict__ rankout,
                                                     int* __restrict__ counts) {
    __shared__ float4 lc[SLIM * 16];     // 16384 B: first SLIM sorted rows
    __shared__ float  lhns[KC];
    __shared__ float  invl[128];         // <=2 batches x 64 dims
    __shared__ unsigned char lks[KC];
    __shared__ int hist[2 * KC];
    __shared__ int gbase[2 * KC];
    int t = threadIdx.x;
    const float4* sc4 = (const float4*)scodes;
    const float4* c4  = (const float4*)codes;
    int bfirst = (blockIdx.x * 256) / NPB;
    for (int i = t; i < SLIM * 16; i += 256) lc[i] = sc4[i];
    for (int i = t; i < KC; i += 256) { lhns[i] = hns[i]; lks[i] = ksrt[i]; }
    if (t < 128) {
        int lb2 = t >> 6, d = t & 63;
        int b2 = bfirst + lb2;
        if (b2 < B_) {
            float s = 0.f;
            #pragma unroll
            for (int o = 0; o < OCT; ++o)
                s += partial[((size_t)(b2 * OCT + o)) * D_ + d];
            invl[t] = 1.f / fmaxf(sqrtf(s), 1e-12f);
        }
    }
    for (int i = t; i < 2 * KC; i += 256) hist[i] = 0;
    __syncthreads();

    int p = blockIdx.x * 256 + t;        // grid exact: 867*256 == NPTS
    int b = p / NPB;
    int lb = b - bfirst;

    float v[D_];
    float q = 0.f;
    {
        const float4* f0 = (const float4*)(feat + (size_t)p * D_);
        const float4* n0 = ((const float4*)invl) + lb * 16;
        #pragma unroll
        for (int j = 0; j < 16; ++j) {
            float4 a = f0[j], w = n0[j];
            v[4*j+0] = a.x * w.x; v[4*j+1] = a.y * w.y;
            v[4*j+2] = a.z * w.z; v[4*j+3] = a.w * w.w;
            q += v[4*j+0]*v[4*j+0] + v[4*j+1]*v[4*j+1]
               + v[4*j+2]*v[4*j+2] + v[4*j+3]*v[4*j+3];
        }
    }
    float bw = sqrtf(q);
    float best = -3.0e38f;
    int kb = 0;
    int i = 0;
    for (; i < SLIM; ++i) {
        float hn = lhns[i];
        float bnd = fmaf(bw, sqrtf(hn + hn), -hn);   // Cauchy-Schwarz bound
        if (__all(bnd + 1e-3f < best)) break;        // monotone in i -> safe
        float a0 = 0.f, a1 = 0.f, a2 = 0.f, a3 = 0.f;
        #pragma unroll
        for (int j = 0; j < 16; ++j) {
            float4 c = lc[i * 16 + j];
            a0 = fmaf(v[4*j+0], c.x, a0); a1 = fmaf(v[4*j+1], c.y, a1);
            a2 = fmaf(v[4*j+2], c.z, a2); a3 = fmaf(v[4*j+3], c.w, a3);
        }
        float s = (a0 + a1) + (a2 + a3) - hn;
        if (s > best) { best = s; kb = i; }
    }
    if (i == SLIM) {                     // rare tail: broadcast reads of codes
        for (; i < KC; ++i) {
            float hn = lhns[i];
            float bnd = fmaf(bw, sqrtf(hn + hn), -hn);
            if (__all(bnd + 1e-3f < best)) break;
            const float4* cr = c4 + (int)lks[i] * 16;
            float a0 = 0.f, a1 = 0.f, a2 = 0.f, a3 = 0.f;
            #pragma unroll
            for (int j = 0; j < 16; ++j) {
                float4 c = cr[j];
                a0 = fmaf(v[4*j+0], c.x, a0); a1 = fmaf(v[4*j+1], c.y, a1);
                a2 = fmaf(v[4*j+2], c.z, a2); a3 = fmaf(v[4*j+3], c.w, a3);
            }
            float s = (a0 + a1) + (a2 + a3) - hn;
            if (s > best) { best = s; kb = i; }
        }
    }
    int k0 = (int)lks[kb];
    float rinv = 1.f / (sqrtf(fmaxf(q - 2.f * best, 0.f)) + 1e-8f);
    kout[p] = (unsigned char)k0;
    rinvout[p] = rinv;
    int rloc = atomicAdd(&hist[lb * KC + k0], 1);    // block-local rank
    __syncthreads();
    for (int j2 = t; j2 < 2 * KC; j2 += 256) {       // reserve global ranges
        int h = hist[j2];
        if (h > 0) gbase[j2] = atomicAdd(&counts[bfirst * KC + j2], h);
    }
    __syncthreads();
    rankout[p] = (unsigned short)(gbase[lb * KC + k0] + rloc);
}

// ===== pass 3: scatter into sorted order (per-block prefix recompute)
__global__ __launch_bounds__(256) void scatter_kernel(const unsigned char* __restrict__ kout,
                                                      const unsigned short* __restrict__ rankout,
                                                      const int* __restrict__ counts,
                                                      unsigned int* __restrict__ spu) {
    __shared__ int lcnt[2 * KC];
    __shared__ int lbase[2 * KC];
    int t = threadIdx.x;
    int bfirst = (blockIdx.x * 256) / NPB, blast = (blockIdx.x * 256 + 255) / NPB;
    int nb = blast - bfirst + 1;                     // 1 or 2
    for (int i = t; i < nb * KC; i += 256) lcnt[i] = counts[bfirst * KC + i];
    __syncthreads();
    if (t < nb) {                                    // serial 248-scan per batch
        int run = 0;
        for (int k = 0; k < KC; ++k) { lbase[t * KC + k] = run; run += lcnt[t * KC + k]; }
    }
    __syncthreads();
    int p = blockIdx.x * 256 + t;
    int b = p / NPB;
    int lb = b - bfirst;
    int k = (int)kout[p];
    int pos = b * NPB + lbase[lb * KC + k] + (int)rankout[p];
    spu[pos] = ((unsigned int)(p - b * NPB) << 8) | (unsigned int)k;
}

// ===== pass 4: load-balanced segmented aggregation (skew-proof)
__global__ __launch_bounds__(256) void aggregate_kernel(const float* __restrict__ feat,
                                                        const unsigned int* __restrict__ spu,
                                                        const float* __restrict__ rinvout,
                                                        float* __restrict__ vacc,
                                                        float* __restrict__ Sacc) {
    int wv = threadIdx.x >> 6, lane = threadIdx.x & 63;
    int chunk = blockIdx.x * 4 + wv;
    if (chunk >= B_ * CHPB) return;
    int b = chunk / CHPB, j = chunk % CHPB;
    int c0 = j * 64;
    int len = NPB - c0; if (len > 64) len = 64;
    int sbase = b * NPB;
    int pos = sbase + c0 + ((lane < len) ? lane : 0);
    unsigned int myu = spu[pos];
    float myr = rinvout[sbase + (int)(myu >> 8)];
    const float* fb = feat + (size_t)sbase * D_ + lane;

    float acc = 0.f, Sr = 0.f;
    int kcur = -1;
    for (int i = 0; i < len; i += 4) {
        int n = len - i; if (n > 4) n = 4;
        float x[4], rr[4];
        int kk[4];
        #pragma unroll
        for (int u = 0; u < 4; ++u) {
            if (u < n) {
                unsigned int uu = __shfl(myu, i + u);
                rr[u] = __shfl(myr, i + u);
                kk[u] = (int)(uu & 255u);
                x[u] = fb[(size_t)(uu >> 8) * D_];
            }
        }
        for (int u = 0; u < n; ++u) {
            if (kk[u] != kcur) {
                if (kcur >= 0) {
                    atomicAdd(vacc + ((size_t)b * KC + kcur) * D_ + lane, acc);
                    if (lane == 0) atomicAdd(Sacc + b * KC + kcur, Sr);
                }
                kcur = kk[u]; acc = 0.f; Sr = 0.f;
            }
            acc = fmaf(x[u], rr[u], acc);
            Sr += rr[u];
        }
    }
    if (kcur >= 0) {
        atomicAdd(vacc + ((size_t)b * KC + kcur) * D_ + lane, acc);
        if (lane == 0) atomicAdd(Sacc + b * KC + kcur, Sr);
    }
}

// ===== pass 5: finalize vlad + per-batch standardize (fused; derives inv-norm)
__global__ __launch_bounds__(1024) void final_std_kernel(const float* __restrict__ vacc,
                                                         const float* __restrict__ Sacc,
                                                         const float* __restrict__ codes,
                                                         const float* __restrict__ partial,
                                                         float* __restrict__ out) {
    __shared__ float val[KC * APAD];   // 64480 B
    __shared__ float Sl[KC];
    __shared__ float invl[D_];
    __shared__ double rs[1024], rss[1024];
    int b = blockIdx.x, t = threadIdx.x;
    if (t < KC) Sl[t] = Sacc[b * KC + t];
    if (t < D_) {
        float s = 0.f;
        #pragma unroll
        for (int o = 0; o < OCT; ++o)
            s += partial[((size_t)(b * OCT + o)) * D_ + t];
        invl[t] = 1.f / fmaxf(sqrtf(s), 1e-12f);
    }
    __syncthreads();
    const float* va = vacc + (size_t)b * NV;
    double s = 0.0, ss = 0.0;
    for (int i = t; i < NV; i += 1024) {
        int k = i >> 6, d = i & 63;
        float v = invl[d] * va[i] - codes[i] * Sl[k];
        val[k * APAD + d] = v;
        s += (double)v;
        ss += (double)v * (double)v;
    }
    rs[t] = s; rss[t] = ss;
    __syncthreads();
    for (int off = 512; off > 0; off >>= 1) {
        if (t < off) { rs[t] += rs[t + off]; rss[t] += rss[t + off]; }
        __syncthreads();
    }
    __shared__ float fmean, fscale;
    if (t == 0) {
        double S = rs[0], SS = rss[0];
        double mean = S / (double)NV;
        double var = (SS - S * S / (double)NV) / (double)(NV - 1);
        double sd = sqrt(var > 0.0 ? var : 0.0);
        fmean = (float)mean;
        fscale = (float)(1.0 / (sd + 1e-8));
    }
    __syncthreads();
    float m = fmean, sc = fscale;
    float* row = out + (size_t)b * NV;
    for (int i = t; i < NV; i += 1024) {
        int k = i >> 6, d = i & 63;
        row[i] = (val[k * APAD + d] - m) * sc;
    }
}

extern "C" void kernel_launch(void* const* d_in, const int* in_sizes, int n_in,
                              void* d_out, int out_size, void* d_ws, size_t ws_size,
                              hipStream_t stream) {
    const float* feat  = (const float*)d_in[0];
    const float* codes = (const float*)d_in[1];
    float* out = (float*)d_out;

    char* ws = (char*)d_ws;
    float* partial        = (float*)(ws + OFF_PARTIAL);
    int*   counts         = (int*)  (ws + OFF_COUNTS);
    float* Sacc           = (float*)(ws + OFF_SACC);
    float* vacc           = (float*)(ws + OFF_VACC);
    float4* zbase         = (float4*)(ws + OFF_COUNTS);
    unsigned char* kout   = (unsigned char*)(ws + OFF_KOUT);
    float* rinvout        = (float*)(ws + OFF_RINV);
    unsigned short* rankp = (unsigned short*)(ws + OFF_RANK);
    unsigned int* spu     = (unsigned int*)(ws + OFF_SPU);
    float* hns            = (float*)(ws + OFF_HNS);
    unsigned char* ksrt   = (unsigned char*)(ws + OFF_KSRT);
    float* scodes         = (float*)(ws + OFF_SCODES);

    hipLaunchKernelGGL(prep_kernel, dim3(SCB + 1 + ZBLK), dim3(256), 0, stream,
                       feat, codes, partial, hns, ksrt, scodes, zbase);
    hipLaunchKernelGGL(assign_kernel, dim3(NBLK), dim3(256), 0, stream,
                       feat, codes, scodes, partial, hns, ksrt,
                       kout, rinvout, rankp, counts);
    hipLaunchKernelGGL(scatter_kernel, dim3(NBLK), dim3(256), 0, stream,
                       kout, rankp, counts, spu);
    hipLaunchKernelGGL(aggregate_kernel, dim3((B_ * CHPB + 3) / 4), dim3(256), 0, stream,
                       feat, spu, rinvout, vacc, Sacc);
    hipLaunchKernelGGL(final_std_kernel, dim3(B_), dim3(1024), 0, stream,
                       vacc, Sacc, codes, partial, out);
}

// Round 15
// 93.428 us; speedup vs baseline: 1.1489x; 1.1489x over previous
//
#include <hip/hip_runtime.h>
#include <math.h>

#define B_   64
#define NPB  3468            // points (visual words) per batch
#define NPTS (B_ * NPB)      // 221952
#define KC   248
#define D_   64
#define NV   (KC * D_)       // 15872 per-batch vlad elements
#define OCT  8               // scan blocks per batch (partials per batch)
#define N4PB (NPB * D_ / 4)  // 55488 float4s per batch (= 6*8192 + 6336)
#define CHPB 55              // aggregation chunks per batch
#define APAD 65
#define SLIM 64              // sorted code rows staged in LDS
#define NBLK (NPTS / 256)    // 867 point-blocks
#define SCANB (B_ * OCT)     // 512 scan blocks (2/CU x 16 waves = 32 waves/CU)
#define ZBLK 128             // zeroing blocks in prep
#define ZN4  261888          // float4s in zero region (counts+Sacc+vacc)

typedef float nf4 __attribute__((ext_vector_type(4)));   // builtin-compatible vec4

// ------------------------- workspace offsets (bytes) -------------------------
#define OFF_PARTIAL 0u        // 64*8*64*4 = 131072
#define OFF_COUNTS  131072u   // 63488   -- zero region start
#define OFF_SACC    194560u   // 63488
#define OFF_VACC    258048u   // 4063232 -- zero region end = 4321280
#define OFF_KOUT    4321280u  // 221952
#define OFF_RINV    4543232u  // 887808
#define OFF_RANK    5431040u  // 443904
#define OFF_SPU     5874944u  // 887808  (packed sorted: pidx<<8 | k)
#define OFF_HNS     6762752u  // 1024
#define OFF_KSRT    6763776u  // 256
#define OFF_SCODES  6764032u  // 16384 (first SLIM sorted rows) -> end 6780416

// ===== pass 1 (1024-thread blocks): max-occupancy scan + code sort + zeroing
__global__ __launch_bounds__(1024) void prep_kernel(const float* __restrict__ feat,
                                                    const float* __restrict__ codes,
                                                    float* __restrict__ partial,
                                                    float* __restrict__ hns,
                                                    unsigned char* __restrict__ ksrt,
                                                    float* __restrict__ scodes,
                                                    float4* __restrict__ zbase) {
    int t = threadIdx.x;
    int lane = t & 63, wvid = t >> 6;
    if (blockIdx.x > SCANB) {               // zeroing blocks
        int z = blockIdx.x - (SCANB + 1);
        const float4 zf = make_float4(0.f, 0.f, 0.f, 0.f);
        for (int i = z * 1024 + t; i < ZN4; i += ZBLK * 1024) zbase[i] = zf;
        return;
    }
    if (blockIdx.x == SCANB) {              // code half-norms + hn-sort block
        __shared__ float shn[KC];
        for (int base2 = 0; base2 < KC * D_; base2 += 1024) {
            int idx = base2 + t;
            float c = (idx < KC * D_) ? codes[idx] : 0.f;
            float cc = c * c;
            #pragma unroll
            for (int off = 32; off > 0; off >>= 1) cc += __shfl_down(cc, off);
            if (lane == 0) {
                int row = (base2 >> 6) + wvid;
                if (row < KC) shn[row] = 0.5f * cc;
            }
        }
        __syncthreads();
        if (t < KC) {
            float myhn = shn[t];
            int rank = 0;
            for (int j = 0; j < KC; ++j) {
                float h = shn[j];
                rank += (h < myhn) || (h == myhn && j < t);
            }
            hns[rank] = myhn;
            ksrt[rank] = (unsigned char)t;
            if (rank < SLIM) {              // stage only rows assign keeps in LDS
                const float4* src = (const float4*)(codes + t * D_);
                float4* dst = (float4*)(scodes + rank * D_);
                #pragma unroll
                for (int j = 0; j < 16; ++j) dst[j] = src[j];
            }
        }
        return;
    }
    // scan: 8 blocks/batch x 1024 threads, stride 8192 (%16==0 -> group = t&15)
    int b = blockIdx.x >> 3, o = blockIdx.x & 7;
    const nf4* fv = (const nf4*)feat + (size_t)b * N4PB;
    int idx0 = o * 1024 + t;
    float ax = 0.f, ay = 0.f, az = 0.f, aw = 0.f;
    {
        nf4 r[6];
        #pragma unroll
        for (int j = 0; j < 6; ++j)                       // 6 loads in flight
            r[j] = __builtin_nontemporal_load(&fv[idx0 + j * 8192]);
        #pragma unroll
        for (int j = 0; j < 6; ++j) {
            ax += r[j].x * r[j].x; ay += r[j].y * r[j].y;
            az += r[j].z * r[j].z; aw += r[j].w * r[j].w;
        }
        if (idx0 < N4PB - 49152) {                        // tail 49152..55487
            nf4 a = __builtin_nontemporal_load(&fv[idx0 + 49152]);
            ax += a.x * a.x; ay += a.y * a.y; az += a.z * a.z; aw += a.w * a.w;
        }
    }
    __shared__ float4 red[1024];            // 16 KB
    red[t] = make_float4(ax, ay, az, aw);
    __syncthreads();
    if (t < 16) {
        float sx = 0.f, sy = 0.f, sz = 0.f, sw = 0.f;
        for (int j = 0; j < 64; ++j) {
            float4 a = red[t + 16 * j];
            sx += a.x; sy += a.y; sz += a.z; sw += a.w;
        }
        float* dst = partial + ((size_t)(b * OCT + o)) * D_ + 4 * t;
        dst[0] = sx; dst[1] = sy; dst[2] = sz; dst[3] = sw;
    }
}

// ===== pass 2: assignment (per-block inv-norm derive + CS pruning + 2-level rank)
__global__ __launch_bounds__(256) void assign_kernel(const float* __restrict__ feat,
                                                     const float* __restrict__ codes,
                                                     const float* __restrict__ scodes,
                                                     const float* __restrict__ partial,
                                                     const float* __restrict__ hns,
                                                     const unsigned char* __restrict__ ksrt,
                                                     unsigned char* __restrict__ kout,
                                                     float* __restrict__ rinvout,
                                                     unsigned short* __restrict__ rankout,
                                                     int* __restrict__ counts) {
    __shared__ float4 lc[SLIM * 16];     // 16384 B: first SLIM sorted rows
    __shared__ float  lhns[KC];
    __shared__ float  invl[128];         // <=2 batches x 64 dims
    __shared__ unsigned char lks[KC];
    __shared__ int hist[2 * KC];
    __shared__ int gbase[2 * KC];
    int t = threadIdx.x;
    const float4* sc4 = (const float4*)scodes;
    const float4* c4  = (const float4*)codes;
    int bfirst = (blockIdx.x * 256) / NPB;
    for (int i = t; i < SLIM * 16; i += 256) lc[i] = sc4[i];
    for (int i = t; i < KC; i += 256) { lhns[i] = hns[i]; lks[i] = ksrt[i]; }
    if (t < 128) {
        int lb2 = t >> 6, d = t & 63;
        int b2 = bfirst + lb2;
        if (b2 < B_) {
            float s = 0.f;
            #pragma unroll
            for (int o = 0; o < OCT; ++o)
                s += partial[((size_t)(b2 * OCT + o)) * D_ + d];
            invl[t] = 1.f / fmaxf(sqrtf(s), 1e-12f);
        }
    }
    for (int i = t; i < 2 * KC; i += 256) hist[i] = 0;
    __syncthreads();

    int p = blockIdx.x * 256 + t;        // grid exact: 867*256 == NPTS
    int b = p / NPB;
    int lb = b - bfirst;

    float v[D_];
    float q = 0.f;
    {
        const float4* f0 = (const float4*)(feat + (size_t)p * D_);
        const float4* n0 = ((const float4*)invl) + lb * 16;
        #pragma unroll
        for (int j = 0; j < 16; ++j) {
            float4 a = f0[j], w = n0[j];
            v[4*j+0] = a.x * w.x; v[4*j+1] = a.y * w.y;
            v[4*j+2] = a.z * w.z; v[4*j+3] = a.w * w.w;
            q += v[4*j+0]*v[4*j+0] + v[4*j+1]*v[4*j+1]
               + v[4*j+2]*v[4*j+2] + v[4*j+3]*v[4*j+3];
        }
    }
    float bw = sqrtf(q);
    float best = -3.0e38f;
    int kb = 0;
    int i = 0;
    for (; i < SLIM; ++i) {
        float hn = lhns[i];
        float bnd = fmaf(bw, sqrtf(hn + hn), -hn);   // Cauchy-Schwarz bound
        if (__all(bnd + 1e-3f < best)) break;        // monotone in i -> safe
        float a0 = 0.f, a1 = 0.f, a2 = 0.f, a3 = 0.f;
        #pragma unroll
        for (int j = 0; j < 16; ++j) {
            float4 c = lc[i * 16 + j];
            a0 = fmaf(v[4*j+0], c.x, a0); a1 = fmaf(v[4*j+1], c.y, a1);
            a2 = fmaf(v[4*j+2], c.z, a2); a3 = fmaf(v[4*j+3], c.w, a3);
        }
        float s = (a0 + a1) + (a2 + a3) - hn;
        if (s > best) { best = s; kb = i; }
    }
    if (i == SLIM) {                     // rare tail: broadcast reads of codes
        for (; i < KC; ++i) {
            float hn = lhns[i];
            float bnd = fmaf(bw, sqrtf(hn + hn), -hn);
            if (__all(bnd + 1e-3f < best)) break;
            const float4* cr = c4 + (int)lks[i] * 16;
            float a0 = 0.f, a1 = 0.f, a2 = 0.f, a3 = 0.f;
            #pragma unroll
            for (int j = 0; j < 16; ++j) {
                float4 c = cr[j];
                a0 = fmaf(v[4*j+0], c.x, a0); a1 = fmaf(v[4*j+1], c.y, a1);
                a2 = fmaf(v[4*j+2], c.z, a2); a3 = fmaf(v[4*j+3], c.w, a3);
            }
            float s = (a0 + a1) + (a2 + a3) - hn;
            if (s > best) { best = s; kb = i; }
        }
    }
    int k0 = (int)lks[kb];
    float rinv = 1.f / (sqrtf(fmaxf(q - 2.f * best, 0.f)) + 1e-8f);
    kout[p] = (unsigned char)k0;
    rinvout[p] = rinv;
    int rloc = atomicAdd(&hist[lb * KC + k0], 1);    // block-local rank
    __syncthreads();
    for (int j2 = t; j2 < 2 * KC; j2 += 256) {       // reserve global ranges
        int h = hist[j2];
        if (h > 0) gbase[j2] = atomicAdd(&counts[bfirst * KC + j2], h);
    }
    __syncthreads();
    rankout[p] = (unsigned short)(gbase[lb * KC + k0] + rloc);
}

// ===== pass 3: scatter into sorted order (per-block prefix recompute)
__global__ __launch_bounds__(256) void scatter_kernel(const unsigned char* __restrict__ kout,
                                                      const unsigned short* __restrict__ rankout,
                                                      const int* __restrict__ counts,
                                                      unsigned int* __restrict__ spu) {
    __shared__ int lcnt[2 * KC];
    __shared__ int lbase[2 * KC];
    int t = threadIdx.x;
    int bfirst = (blockIdx.x * 256) / NPB, blast = (blockIdx.x * 256 + 255) / NPB;
    int nb = blast - bfirst + 1;                     // 1 or 2
    for (int i = t; i < nb * KC; i += 256) lcnt[i] = counts[bfirst * KC + i];
    __syncthreads();
    if (t < nb) {                                    // serial 248-scan per batch
        int run = 0;
        for (int k = 0; k < KC; ++k) { lbase[t * KC + k] = run; run += lcnt[t * KC + k]; }
    }
    __syncthreads();
    int p = blockIdx.x * 256 + t;
    int b = p / NPB;
    int lb = b - bfirst;
    int k = (int)kout[p];
    int pos = b * NPB + lbase[lb * KC + k] + (int)rankout[p];
    spu[pos] = ((unsigned int)(p - b * NPB) << 8) | (unsigned int)k;
}

// ===== pass 4: load-balanced segmented aggregation (skew-proof)
__global__ __launch_bounds__(256) void aggregate_kernel(const float* __restrict__ feat,
                                                        const unsigned int* __restrict__ spu,
                                                        const float* __restrict__ rinvout,
                                                        float* __restrict__ vacc,
                                                        float* __restrict__ Sacc) {
    int wv = threadIdx.x >> 6, lane = threadIdx.x & 63;
    int chunk = blockIdx.x * 4 + wv;
    if (chunk >= B_ * CHPB) return;
    int b = chunk / CHPB, j = chunk % CHPB;
    int c0 = j * 64;
    int len = NPB - c0; if (len > 64) len = 64;
    int sbase = b * NPB;
    int pos = sbase + c0 + ((lane < len) ? lane : 0);
    unsigned int myu = spu[pos];
    float myr = rinvout[sbase + (int)(myu >> 8)];
    const float* fb = feat + (size_t)sbase * D_ + lane;

    float acc = 0.f, Sr = 0.f;
    int kcur = -1;
    for (int i = 0; i < len; i += 4) {
        int n = len - i; if (n > 4) n = 4;
        float x[4], rr[4];
        int kk[4];
        #pragma unroll
        for (int u = 0; u < 4; ++u) {
            if (u < n) {
                unsigned int uu = __shfl(myu, i + u);
                rr[u] = __shfl(myr, i + u);
                kk[u] = (int)(uu & 255u);
                x[u] = fb[(size_t)(uu >> 8) * D_];
            }
        }
        for (int u = 0; u < n; ++u) {
            if (kk[u] != kcur) {
                if (kcur >= 0) {
                    atomicAdd(vacc + ((size_t)b * KC + kcur) * D_ + lane, acc);
                    if (lane == 0) atomicAdd(Sacc + b * KC + kcur, Sr);
                }
                kcur = kk[u]; acc = 0.f; Sr = 0.f;
            }
            acc = fmaf(x[u], rr[u], acc);
            Sr += rr[u];
        }
    }
    if (kcur >= 0) {
        atomicAdd(vacc + ((size_t)b * KC + kcur) * D_ + lane, acc);
        if (lane == 0) atomicAdd(Sacc + b * KC + kcur, Sr);
    }
}

// ===== pass 5: finalize vlad + per-batch standardize (fused; derives inv-norm)
__global__ __launch_bounds__(1024) void final_std_kernel(const float* __restrict__ vacc,
                                                         const float* __restrict__ Sacc,
                                                         const float* __restrict__ codes,
                                                         const float* __restrict__ partial,
                                                         float* __restrict__ out) {
    __shared__ float val[KC * APAD];   // 64480 B
    __shared__ float Sl[KC];
    __shared__ float invl[D_];
    __shared__ double rs[1024], rss[1024];
    int b = blockIdx.x, t = threadIdx.x;
    if (t < KC) Sl[t] = Sacc[b * KC + t];
    if (t < D_) {
        float s = 0.f;
        #pragma unroll
        for (int o = 0; o < OCT; ++o)
            s += partial[((size_t)(b * OCT + o)) * D_ + t];
        invl[t] = 1.f / fmaxf(sqrtf(s), 1e-12f);
    }
    __syncthreads();
    const float* va = vacc + (size_t)b * NV;
    double s = 0.0, ss = 0.0;
    for (int i = t; i < NV; i += 1024) {
        int k = i >> 6, d = i & 63;
        float v = invl[d] * va[i] - codes[i] * Sl[k];
        val[k * APAD + d] = v;
        s += (double)v;
        ss += (double)v * (double)v;
    }
    rs[t] = s; rss[t] = ss;
    __syncthreads();
    for (int off = 512; off > 0; off >>= 1) {
        if (t < off) { rs[t] += rs[t + off]; rss[t] += rss[t + off]; }
        __syncthreads();
    }
    __shared__ float fmean, fscale;
    if (t == 0) {
        double S = rs[0], SS = rss[0];
        double mean = S / (double)NV;
        double var = (SS - S * S / (double)NV) / (double)(NV - 1);
        double sd = sqrt(var > 0.0 ? var : 0.0);
        fmean = (float)mean;
        fscale = (float)(1.0 / (sd + 1e-8));
    }
    __syncthreads();
    float m = fmean, sc = fscale;
    float* row = out + (size_t)b * NV;
    for (int i = t; i < NV; i += 1024) {
        int k = i >> 6, d = i & 63;
        row[i] = (val[k * APAD + d] - m) * sc;
    }
}

extern "C" void kernel_launch(void* const* d_in, const int* in_sizes, int n_in,
                              void* d_out, int out_size, void* d_ws, size_t ws_size,
                              hipStream_t stream) {
    const float* feat  = (const float*)d_in[0];
    const float* codes = (const float*)d_in[1];
    float* out = (float*)d_out;

    char* ws = (char*)d_ws;
    float* partial        = (float*)(ws + OFF_PARTIAL);
    int*   counts         = (int*)  (ws + OFF_COUNTS);
    float* Sacc           = (float*)(ws + OFF_SACC);
    float* vacc           = (float*)(ws + OFF_VACC);
    float4* zbase         = (float4*)(ws + OFF_COUNTS);
    unsigned char* kout   = (unsigned char*)(ws + OFF_KOUT);
    float* rinvout        = (float*)(ws + OFF_RINV);
    unsigned short* rankp = (unsigned short*)(ws + OFF_RANK);
    unsigned int* spu     = (unsigned int*)(ws + OFF_SPU);
    float* hns            = (float*)(ws + OFF_HNS);
    unsigned char* ksrt   = (unsigned char*)(ws + OFF_KSRT);
    float* scodes         = (float*)(ws + OFF_SCODES);

    hipLaunchKernelGGL(prep_kernel, dim3(SCANB + 1 + ZBLK), dim3(1024), 0, stream,
                       feat, codes, partial, hns, ksrt, scodes, zbase);
    hipLaunchKernelGGL(assign_kernel, dim3(NBLK), dim3(256), 0, stream,
                       feat, codes, scodes, partial, hns, ksrt,
                       kout, rinvout, rankp, counts);
    hipLaunchKernelGGL(scatter_kernel, dim3(NBLK), dim3(256), 0, stream,
                       kout, rankp, counts, spu);
    hipLaunchKernelGGL(aggregate_kernel, dim3((B_ * CHPB + 3) / 4), dim3(256), 0, stream,
                       feat, spu, rinvout, vacc, Sacc);
    hipLaunchKernelGGL(final_std_kernel, dim3(B_), dim3(1024), 0, stream,
                       vacc, Sacc, codes, partial, out);
}